// Round 9
// baseline (17.584 us; speedup 1.0000x reference)
//
#include <hip/hip_runtime.h>

#define B_ 8
#define LQ_ 64
#define LK_ 256
#define E_ 128
#define H_ 4
#define D_ 32
#define NH_ 128
#define EK_ 32

// ---------------------------------------------------------------------------
// Round-13: R11 (16.16us, best) + two round-trip deletions, nothing else.
// R12 lesson: remaps that shuffle work between pipes net ~0 or negative;
// only deletions of whole round-trips have paid. Changes vs R11:
//  (1) phases 2+3 merged: thread (col'=t>>2, zz=t&3) computes both rows'
//      slab-partials, cross-slab sum via 2x shfl_xor(1,2) in-wave (zz in
//      adjacent lanes) -> qpart LDS round-trip (1024w+1280r) and one
//      barrier deleted. bq hoisted to reg in phase 0.
//  (2) phase 8: in-wave kg-pair combine via shfl_xor(32) (lanes l, l^32 hold
//      kg, kg^1 at same d) -> nump/denp writes 8192->4096, phase-9 reads
//      halved. (The isolated-safe half of R12.)
// Phases 4-7, 10-11, LDS layout, load issue order, raw barriers, XCD
// swizzle: R11-exact.
// ---------------------------------------------------------------------------

#define RAW_BARRIER() asm volatile("s_waitcnt lgkmcnt(0)\n\ts_barrier" ::: "memory")

__global__ __launch_bounds__(512, 2) void fused_attn_kernel(
    const float* __restrict__ query, const float* __restrict__ key,
    const float* __restrict__ value, const int* __restrict__ mask,
    const float* __restrict__ Wq, const float* __restrict__ bq,
    const float* __restrict__ Wk,
    const float* __restrict__ Wo, const float* __restrict__ bo,
    float* __restrict__ out)
{
    const int blk0 = blockIdx.x;              // 256 blocks
    const int blk  = (blk0 & 7) * 32 + (blk0 >> 3);   // XCD-chunked bijection
    const int b  = blk >> 5;                  // batch per XCD
    const int q0 = (blk & 31) * 2;
    const int t  = threadIdx.x;

    extern __shared__ float dyn[];            // 35328 floats = 138 KB
    float* qrow  = dyn;                       // 256            (1-2)
    // dyn+256 .. dyn+1280 : (qpart slot, now unused)
    float* qp    = dyn + 1280;                // 256            (2-4)
    float* g     = dyn + 1536;                // 1024           (4-5)
    float* kt    = dyn + 2560;                // 32768 = 128KB  (0-5a)
    float* spart = dyn + 2560;                // 8192  (alias)  (5b-6)
    float* e_lds = dyn + 10752;               // 2048  (alias)  (7-8)
    float* nump  = dyn + 12800;               // 2048  (alias)  (8-9)
    float* denp  = dyn + 16896;               // 2048  (alias)  (8-9)
    float* x     = dyn + 20992;               // 256   (alias)  (9-10)
    float* opart = dyn + 21248;               // 1024  (alias)  (10-11)

    // ================= phase 0: issue loads in consumption order ===========
    // (1) query (consumed phase 1)
    float4 qv0;
    if (t < 64)
        qv0 = reinterpret_cast<const float4*>(
            query + ((size_t)(b * LQ_) + q0) * E_)[t];

    // (2) bq scalar + Wq fragment -> regs (consumed phase 2).
    // phase-2 mapping: colq = t>>2 (0..127), zz = t&3 (e-slab, in-lane).
    const int colq = t >> 2;
    const int zz   = t & 3;
    const float bqv = bq[colq];
    float wqr[32];
    {
        const float* wqp = Wq + (size_t)(zz * 32) * E_ + colq;
        #pragma unroll
        for (int j = 0; j < 32; ++j) wqr[j] = wqp[(size_t)j * E_];
    }

    // (3) Wk fragment -> regs (consumed phase 4). e4=t>>2, p4=t&3.
    const int e4 = t >> 2, p4 = t & 3;
    float4 wkr[8];
    {
        const float4* wk4 =
            reinterpret_cast<const float4*>(Wk + (size_t)e4 * E_ + p4 * EK_);
        #pragma unroll
        for (int j = 0; j < 8; ++j) wkr[j] = wk4[j];
    }

    // (4) key -> kt via global_load_lds, pre-swizzled source (consumed 5a).
    // kt_linear[slot=k*32+p] <- key[b][k][f4 (p ^ (k&7))]
    {
        const float4* kb4 =
            reinterpret_cast<const float4*>(key + (size_t)b * LK_ * E_);
        #pragma unroll
        for (int i = 0; i < 16; ++i) {
            const int slot = i * 512 + t;
            const int k = slot >> 5;
            const int p = slot & 31;
            const float4* src = kb4 + (k * 32 + (p ^ (k & 7)));
            __builtin_amdgcn_global_load_lds(
                (const __attribute__((address_space(1))) void*)src,
                (__attribute__((address_space(3))) void*)(&kt[slot * 4]),
                16, 0, 0);
        }
    }

    // (5) value/mask -> regs (consumed phase 8)
    const int d  = t & 31;
    const int kg = t >> 5;                    // 16 k-groups of 16
    float vv[16], mfv[16];
    {
        const float* vb = value + ((size_t)(b * LK_) + kg * 16) * D_ + d;
        const int*   mb = mask  + ((size_t)(b * LK_) + kg * 16) * D_ + d;
        #pragma unroll
        for (int j = 0; j < 16; ++j) {
            vv[j]  = vb[j * D_];
            mfv[j] = (float)mb[j * D_];
        }
    }

    // (6) Wo fragment -> regs (consumed phase 10). col2=t&127, slab2=t>>7.
    const int col2  = t & 127;
    const int slab2 = t >> 7;                 // 0..3
    float wor[32];
    {
        const float* wop = Wo + (size_t)(slab2 * 32) * NH_ + col2;
        #pragma unroll
        for (int j = 0; j < 32; ++j) wor[j] = wop[(size_t)j * NH_];
    }

    // ================= phase 1: query rows -> LDS ===========================
    if (t < 64) {
        reinterpret_cast<float4*>(qrow)[t] = qv0;   // waits query only
    }
    RAW_BARRIER();

    // ================= phase 2+3: qp merged (Wq regs, shfl cross-slab) =====
    // thread (colq, zz): slab-partials for BOTH rows; lanes t^1,t^2 hold the
    // other slabs of the same colq -> butterfly sum in-wave; zz==0 writes.
    {
        const float4* qr0 = reinterpret_cast<const float4*>(qrow + zz * 32);
        const float4* qr1 = reinterpret_cast<const float4*>(qrow + 128 + zz * 32);
        float acc0 = 0.0f, acc1 = 0.0f;
        #pragma unroll
        for (int j = 0; j < 8; ++j) {
            float4 q0v = qr0[j];
            float4 q1v = qr1[j];
            const float w0 = wqr[j * 4 + 0];
            const float w1 = wqr[j * 4 + 1];
            const float w2 = wqr[j * 4 + 2];
            const float w3 = wqr[j * 4 + 3];
            acc0 = fmaf(q0v.x, w0, acc0); acc1 = fmaf(q1v.x, w0, acc1);
            acc0 = fmaf(q0v.y, w1, acc0); acc1 = fmaf(q1v.y, w1, acc1);
            acc0 = fmaf(q0v.z, w2, acc0); acc1 = fmaf(q1v.z, w2, acc1);
            acc0 = fmaf(q0v.w, w3, acc0); acc1 = fmaf(q1v.w, w3, acc1);
        }
        acc0 += __shfl_xor(acc0, 1); acc0 += __shfl_xor(acc0, 2);
        acc1 += __shfl_xor(acc1, 1); acc1 += __shfl_xor(acc1, 2);
        if (zz == 0) {
            qp[colq]       = acc0 + bqv;
            qp[128 + colq] = acc1 + bqv;
        }
    }
    RAW_BARRIER();

    // ================= phase 4: g[rh][e] (Wk from regs) =====================
    {
        const float inv_sqrt_ek = 0.17677669529663687f;  // 1/sqrt(32)
        #pragma unroll
        for (int r = 0; r < 2; ++r) {
            const float4* qp4 = reinterpret_cast<const float4*>(qp + r * 128 + p4 * EK_);
            float acc = 0.0f;
            #pragma unroll
            for (int j = 0; j < 8; ++j) {
                float4 pv = qp4[j];
                acc = fmaf(wkr[j].x, pv.x, acc);
                acc = fmaf(wkr[j].y, pv.y, acc);
                acc = fmaf(wkr[j].z, pv.z, acc);
                acc = fmaf(wkr[j].w, pv.w, acc);
            }
            g[(r * 4 + p4) * 128 + e4] = acc * inv_sqrt_ek;
        }
    }
    __syncthreads();   // FULL drain: kt (global_load_lds) must be complete

    // ================= phase 5a: score partials (R11-exact) =================
    const int k5  = t & 127;
    const int eq5 = t >> 7;                   // 0..3
    float acc0[8] = {0.f, 0.f, 0.f, 0.f, 0.f, 0.f, 0.f, 0.f};
    float acc1[8] = {0.f, 0.f, 0.f, 0.f, 0.f, 0.f, 0.f, 0.f};
    {
        const int xr = k5 & 7;                // == (k5+128)&7
        const float4* kt4 = reinterpret_cast<const float4*>(kt);
        const float4* g4  = reinterpret_cast<const float4*>(g);
        #pragma unroll
        for (int j = 0; j < 8; ++j) {
            const int jj = eq5 * 8 + j;
            const float4 kv0 = kt4[k5 * 32 + (jj ^ xr)];
            const float4 kv1 = kt4[(k5 + 128) * 32 + (jj ^ xr)];
            #pragma unroll
            for (int rh = 0; rh < 8; ++rh) {
                const float4 gg = g4[rh * 32 + jj];
                acc0[rh] = fmaf(kv0.x, gg.x, acc0[rh]);
                acc0[rh] = fmaf(kv0.y, gg.y, acc0[rh]);
                acc0[rh] = fmaf(kv0.z, gg.z, acc0[rh]);
                acc0[rh] = fmaf(kv0.w, gg.w, acc0[rh]);
                acc1[rh] = fmaf(kv1.x, gg.x, acc1[rh]);
                acc1[rh] = fmaf(kv1.y, gg.y, acc1[rh]);
                acc1[rh] = fmaf(kv1.z, gg.z, acc1[rh]);
                acc1[rh] = fmaf(kv1.w, gg.w, acc1[rh]);
            }
        }
    }
    __syncthreads();                          // kt dead -> spart may alias

    // ================= phase 5b: write spart ================================
    #pragma unroll
    for (int rh = 0; rh < 8; ++rh) {
        spart[(eq5 * 8 + rh) * 256 + k5]       = acc0[rh];
        spart[(eq5 * 8 + rh) * 256 + k5 + 128] = acc1[rh];
    }
    __syncthreads();

    // ================= phase 6+7: combine + max + exp =======================
    {
        const int w = t >> 6;                 // rh
        const int l = t & 63;                 // k-quad
        const float4* sp4 = reinterpret_cast<const float4*>(spart);
        float4 s0 = sp4[w * 64 + l];
        #pragma unroll
        for (int eq = 1; eq < 4; ++eq) {
            float4 s1 = sp4[(eq * 8 + w) * 64 + l];
            s0.x += s1.x; s0.y += s1.y; s0.z += s1.z; s0.w += s1.w;
        }
        float m = fmaxf(fmaxf(s0.x, s0.y), fmaxf(s0.z, s0.w));
        #pragma unroll
        for (int off = 32; off; off >>= 1)
            m = fmaxf(m, __shfl_xor(m, off));
        float4 e;
        e.x = __expf(s0.x - m); e.y = __expf(s0.y - m);
        e.z = __expf(s0.z - m); e.w = __expf(s0.w - m);
        *reinterpret_cast<float4*>(&e_lds[w * LK_ + l * 4]) = e;
    }
    __syncthreads();

    // ================= phase 8: masked num/den + in-wave kg-pair combine ====
    {
        float num[8] = {0.f,0.f,0.f,0.f,0.f,0.f,0.f,0.f};
        float den[8] = {0.f,0.f,0.f,0.f,0.f,0.f,0.f,0.f};
        #pragma unroll
        for (int jq = 0; jq < 4; ++jq) {
            const float4 mv4 = make_float4(mfv[jq*4+0]*vv[jq*4+0], mfv[jq*4+1]*vv[jq*4+1],
                                           mfv[jq*4+2]*vv[jq*4+2], mfv[jq*4+3]*vv[jq*4+3]);
            const float4 mf4 = make_float4(mfv[jq*4+0], mfv[jq*4+1],
                                           mfv[jq*4+2], mfv[jq*4+3]);
            #pragma unroll
            for (int rh = 0; rh < 8; ++rh) {
                float4 ev = *reinterpret_cast<const float4*>(
                    &e_lds[rh * LK_ + kg * 16 + jq * 4]);
                num[rh] = fmaf(ev.x, mv4.x, num[rh]);
                num[rh] = fmaf(ev.y, mv4.y, num[rh]);
                num[rh] = fmaf(ev.z, mv4.z, num[rh]);
                num[rh] = fmaf(ev.w, mv4.w, num[rh]);
                den[rh] = fmaf(ev.x, mf4.x, den[rh]);
                den[rh] = fmaf(ev.y, mf4.y, den[rh]);
                den[rh] = fmaf(ev.z, mf4.z, den[rh]);
                den[rh] = fmaf(ev.w, mf4.w, den[rh]);
            }
        }
        // lanes l and l^32 hold kg and kg^1 (same d): combine pairs in-wave
        #pragma unroll
        for (int rh = 0; rh < 8; ++rh) {
            num[rh] += __shfl_xor(num[rh], 32);
            den[rh] += __shfl_xor(den[rh], 32);
        }
        if ((kg & 1) == 0) {
            const int kgp = kg >> 1;          // 0..7
            #pragma unroll
            for (int rh = 0; rh < 8; ++rh) {
                nump[(kgp * 8 + rh) * 32 + d] = num[rh];
                denp[(kgp * 8 + rh) * 32 + d] = den[rh];
            }
        }
    }
    __syncthreads();

    // ================= phase 9: x = num/den =================================
    if (t < 256) {
        const int rh = t >> 5, dd = t & 31;
        float n = 0.f, dn = 0.f;
        #pragma unroll
        for (int k2 = 0; k2 < 8; ++k2) {
            n  += nump[(k2 * 8 + rh) * 32 + dd];
            dn += denp[(k2 * 8 + rh) * 32 + dd];
        }
        x[(rh >> 2) * 128 + (rh & 3) * 32 + dd] = n / dn;
    }
    __syncthreads();

    // ================= phase 10: out projection (Wo from regs) ==============
    {
        const int c0 = slab2 * 32;
        const float4* x40 = reinterpret_cast<const float4*>(x + c0);
        const float4* x41 = reinterpret_cast<const float4*>(x + 128 + c0);
        float acc0o = 0.f, acc1o = 0.f;
        #pragma unroll
        for (int j = 0; j < 8; ++j) {
            float4 xv0 = x40[j];
            float4 xv1 = x41[j];
            const float w0 = wor[j * 4 + 0];
            const float w1 = wor[j * 4 + 1];
            const float w2 = wor[j * 4 + 2];
            const float w3 = wor[j * 4 + 3];
            acc0o = fmaf(xv0.x, w0, acc0o); acc1o = fmaf(xv1.x, w0, acc1o);
            acc0o = fmaf(xv0.y, w1, acc0o); acc1o = fmaf(xv1.y, w1, acc1o);
            acc0o = fmaf(xv0.z, w2, acc0o); acc1o = fmaf(xv1.z, w2, acc1o);
            acc0o = fmaf(xv0.w, w3, acc0o); acc1o = fmaf(xv1.w, w3, acc1o);
        }
        opart[(slab2 * 2 + 0) * 128 + col2] = acc0o;
        opart[(slab2 * 2 + 1) * 128 + col2] = acc1o;
    }
    __syncthreads();

    // ================= phase 11: finalize + store ===========================
    if (t < 256) {
        const int col = t & 127, r = t >> 7;
        float s = bo[col];
        #pragma unroll
        for (int eq = 0; eq < 4; ++eq)
            s += opart[(eq * 2 + r) * 128 + col];
        out[((size_t)(b * LQ_) + q0 + r) * NH_ + col] = s;
    }
}

extern "C" void kernel_launch(void* const* d_in, const int* in_sizes, int n_in,
                              void* d_out, int out_size, void* d_ws, size_t ws_size,
                              hipStream_t stream) {
    const float* query = (const float*)d_in[0];
    const float* key   = (const float*)d_in[1];
    const float* value = (const float*)d_in[2];
    const int*   mask  = (const int*)d_in[3];
    const float* Wq    = (const float*)d_in[4];
    const float* bq    = (const float*)d_in[5];
    const float* Wk    = (const float*)d_in[6];
    // d_in[7] = bk: k-constant in scores -> cancels in softmax -> unused
    const float* Wo    = (const float*)d_in[8];
    const float* bo    = (const float*)d_in[9];
    float* out = (float*)d_out;

    const size_t lds_bytes = 35328 * sizeof(float);   // 138 KB
    static bool attr_set = false;
    if (!attr_set) {
        hipFuncSetAttribute(reinterpret_cast<const void*>(fused_attn_kernel),
                            hipFuncAttributeMaxDynamicSharedMemorySize,
                            (int)lds_bytes);
        attr_set = true;
    }

    fused_attn_kernel<<<B_ * (LQ_ / 2), 512, lds_bytes, stream>>>(
        query, key, value, mask, Wq, bq, Wk, Wo, bo, out);
}

// Round 10
// 16.162 us; speedup vs baseline: 1.0880x; 1.0880x over previous
//
#include <hip/hip_runtime.h>

#define B_ 8
#define LQ_ 64
#define LK_ 256
#define E_ 128
#define H_ 4
#define D_ 32
#define NH_ 128
#define EK_ 32

// ---------------------------------------------------------------------------
// Round-14: restore R11 verbatim (session best, 16.16us).
// R12 (LDS-op remap) and R13 (round-trip merges) both regressed: every
// remaining local transformation's secondary cost (coalescing, registers,
// barriers) exceeds its primary saving. R11 = the structural floor found:
//  - key staged HBM->LDS at the coalescing floor via global_load_lds with
//    pre-swizzled source (conflict-free XOR layout on read).
//  - all weights register-hoisted in consumption order; raw lgkmcnt-only
//    barriers between phases 1-4 keep the load stream in flight.
//  - single full drain at 4->5 (global_load_lds completion).
//  - XCD-batch swizzle: one batch per XCD L2.
// ---------------------------------------------------------------------------

#define RAW_BARRIER() asm volatile("s_waitcnt lgkmcnt(0)\n\ts_barrier" ::: "memory")

__global__ __launch_bounds__(512, 2) void fused_attn_kernel(
    const float* __restrict__ query, const float* __restrict__ key,
    const float* __restrict__ value, const int* __restrict__ mask,
    const float* __restrict__ Wq, const float* __restrict__ bq,
    const float* __restrict__ Wk,
    const float* __restrict__ Wo, const float* __restrict__ bo,
    float* __restrict__ out)
{
    const int blk0 = blockIdx.x;              // 256 blocks
    const int blk  = (blk0 & 7) * 32 + (blk0 >> 3);   // XCD-chunked bijection
    const int b  = blk >> 5;                  // batch per XCD
    const int q0 = (blk & 31) * 2;
    const int t  = threadIdx.x;

    extern __shared__ float dyn[];            // 35328 floats = 138 KB
    float* qrow  = dyn;                       // 256            (1-2)
    float* qpart = dyn + 256;                 // 1024           (2-3)
    float* qp    = dyn + 1280;                // 256            (3-4)
    float* g     = dyn + 1536;                // 1024           (4-5)
    float* kt    = dyn + 2560;                // 32768 = 128KB  (0-5a)
    float* spart = dyn + 2560;                // 8192  (alias)  (5b-6)
    float* e_lds = dyn + 10752;               // 2048  (alias)  (7-8)
    float* nump  = dyn + 12800;               // 4096  (alias)  (8-9)
    float* denp  = dyn + 16896;               // 4096  (alias)  (8-9)
    float* x     = dyn + 20992;               // 256   (alias)  (9-10)
    float* opart = dyn + 21248;               // 1024  (alias)  (10-11)

    // ================= phase 0: issue loads in consumption order ===========
    // (1) query (consumed phase 1)
    float4 qv0;
    if (t < 64)
        qv0 = reinterpret_cast<const float4*>(
            query + ((size_t)(b * LQ_) + q0) * E_)[t];

    // (2) Wq fragment -> regs (consumed phase 2). col=t&127, slab=t>>7.
    const int col2  = t & 127;
    const int slab2 = t >> 7;                 // 0..3
    float wqr[32];
    {
        const float* wqp = Wq + (size_t)(slab2 * 32) * E_ + col2;
        #pragma unroll
        for (int j = 0; j < 32; ++j) wqr[j] = wqp[(size_t)j * E_];
    }

    // (3) Wk fragment -> regs (consumed phase 4). e4=t>>2, p4=t&3.
    const int e4 = t >> 2, p4 = t & 3;
    float4 wkr[8];
    {
        const float4* wk4 =
            reinterpret_cast<const float4*>(Wk + (size_t)e4 * E_ + p4 * EK_);
        #pragma unroll
        for (int j = 0; j < 8; ++j) wkr[j] = wk4[j];
    }

    // (4) key -> kt via global_load_lds, pre-swizzled source (consumed 5a).
    // kt_linear[slot=k*32+p] <- key[b][k][f4 (p ^ (k&7))]
    {
        const float4* kb4 =
            reinterpret_cast<const float4*>(key + (size_t)b * LK_ * E_);
        #pragma unroll
        for (int i = 0; i < 16; ++i) {
            const int slot = i * 512 + t;
            const int k = slot >> 5;
            const int p = slot & 31;
            const float4* src = kb4 + (k * 32 + (p ^ (k & 7)));
            __builtin_amdgcn_global_load_lds(
                (const __attribute__((address_space(1))) void*)src,
                (__attribute__((address_space(3))) void*)(&kt[slot * 4]),
                16, 0, 0);
        }
    }

    // (5) value/mask -> regs (consumed phase 8)
    const int d  = t & 31;
    const int kg = t >> 5;                    // 16 k-groups of 16
    float vv[16], mfv[16];
    {
        const float* vb = value + ((size_t)(b * LK_) + kg * 16) * D_ + d;
        const int*   mb = mask  + ((size_t)(b * LK_) + kg * 16) * D_ + d;
        #pragma unroll
        for (int j = 0; j < 16; ++j) {
            vv[j]  = vb[j * D_];
            mfv[j] = (float)mb[j * D_];
        }
    }

    // (6) Wo fragment -> regs (consumed phase 10). Same (col,slab) mapping.
    float wor[32];
    {
        const float* wop = Wo + (size_t)(slab2 * 32) * NH_ + col2;
        #pragma unroll
        for (int j = 0; j < 32; ++j) wor[j] = wop[(size_t)j * NH_];
    }

    // ================= phase 1: query rows -> LDS ===========================
    if (t < 64) {
        reinterpret_cast<float4*>(qrow)[t] = qv0;   // waits query only
    }
    RAW_BARRIER();

    // ================= phase 2: qp partials (Wq from regs) ==================
    {
        const float4* qr0 = reinterpret_cast<const float4*>(qrow + slab2 * 32);
        const float4* qr1 = reinterpret_cast<const float4*>(qrow + 128 + slab2 * 32);
        float acc0 = 0.0f, acc1 = 0.0f;
        #pragma unroll
        for (int j = 0; j < 8; ++j) {
            float4 q0v = qr0[j];
            float4 q1v = qr1[j];
            const float w0 = wqr[j * 4 + 0];
            const float w1 = wqr[j * 4 + 1];
            const float w2 = wqr[j * 4 + 2];
            const float w3 = wqr[j * 4 + 3];
            acc0 = fmaf(q0v.x, w0, acc0); acc1 = fmaf(q1v.x, w0, acc1);
            acc0 = fmaf(q0v.y, w1, acc0); acc1 = fmaf(q1v.y, w1, acc1);
            acc0 = fmaf(q0v.z, w2, acc0); acc1 = fmaf(q1v.z, w2, acc1);
            acc0 = fmaf(q0v.w, w3, acc0); acc1 = fmaf(q1v.w, w3, acc1);
        }
        qpart[(slab2 * 2 + 0) * 128 + col2] = acc0;
        qpart[(slab2 * 2 + 1) * 128 + col2] = acc1;
    }
    RAW_BARRIER();

    // ================= phase 3: qp finalize =================================
    if (t < 256) {
        const int col = t & 127, r = t >> 7;
        float s = bq[col];
        #pragma unroll
        for (int slab = 0; slab < 4; ++slab)
            s += qpart[(slab * 2 + r) * 128 + col];
        qp[r * 128 + col] = s;
    }
    RAW_BARRIER();

    // ================= phase 4: g[rh][e] (Wk from regs) =====================
    {
        const float inv_sqrt_ek = 0.17677669529663687f;  // 1/sqrt(32)
        #pragma unroll
        for (int r = 0; r < 2; ++r) {
            const float4* qp4 = reinterpret_cast<const float4*>(qp + r * 128 + p4 * EK_);
            float acc = 0.0f;
            #pragma unroll
            for (int j = 0; j < 8; ++j) {
                float4 pv = qp4[j];
                acc = fmaf(wkr[j].x, pv.x, acc);
                acc = fmaf(wkr[j].y, pv.y, acc);
                acc = fmaf(wkr[j].z, pv.z, acc);
                acc = fmaf(wkr[j].w, pv.w, acc);
            }
            g[(r * 4 + p4) * 128 + e4] = acc * inv_sqrt_ek;
        }
    }
    __syncthreads();   // FULL drain: kt (global_load_lds) must be complete

    // ================= phase 5a: score partials =============================
    const int k5  = t & 127;
    const int eq5 = t >> 7;                   // 0..3
    float acc0[8] = {0.f, 0.f, 0.f, 0.f, 0.f, 0.f, 0.f, 0.f};
    float acc1[8] = {0.f, 0.f, 0.f, 0.f, 0.f, 0.f, 0.f, 0.f};
    {
        const int xr = k5 & 7;                // == (k5+128)&7
        const float4* kt4 = reinterpret_cast<const float4*>(kt);
        const float4* g4  = reinterpret_cast<const float4*>(g);
        #pragma unroll
        for (int j = 0; j < 8; ++j) {
            const int jj = eq5 * 8 + j;
            const float4 kv0 = kt4[k5 * 32 + (jj ^ xr)];
            const float4 kv1 = kt4[(k5 + 128) * 32 + (jj ^ xr)];
            #pragma unroll
            for (int rh = 0; rh < 8; ++rh) {
                const float4 gg = g4[rh * 32 + jj];
                acc0[rh] = fmaf(kv0.x, gg.x, acc0[rh]);
                acc0[rh] = fmaf(kv0.y, gg.y, acc0[rh]);
                acc0[rh] = fmaf(kv0.z, gg.z, acc0[rh]);
                acc0[rh] = fmaf(kv0.w, gg.w, acc0[rh]);
                acc1[rh] = fmaf(kv1.x, gg.x, acc1[rh]);
                acc1[rh] = fmaf(kv1.y, gg.y, acc1[rh]);
                acc1[rh] = fmaf(kv1.z, gg.z, acc1[rh]);
                acc1[rh] = fmaf(kv1.w, gg.w, acc1[rh]);
            }
        }
    }
    __syncthreads();                          // kt dead -> spart may alias

    // ================= phase 5b: write spart ================================
    #pragma unroll
    for (int rh = 0; rh < 8; ++rh) {
        spart[(eq5 * 8 + rh) * 256 + k5]       = acc0[rh];
        spart[(eq5 * 8 + rh) * 256 + k5 + 128] = acc1[rh];
    }
    __syncthreads();

    // ================= phase 6+7: combine + max + exp =======================
    {
        const int w = t >> 6;                 // rh
        const int l = t & 63;                 // k-quad
        const float4* sp4 = reinterpret_cast<const float4*>(spart);
        float4 s0 = sp4[w * 64 + l];
        #pragma unroll
        for (int eq = 1; eq < 4; ++eq) {
            float4 s1 = sp4[(eq * 8 + w) * 64 + l];
            s0.x += s1.x; s0.y += s1.y; s0.z += s1.z; s0.w += s1.w;
        }
        float m = fmaxf(fmaxf(s0.x, s0.y), fmaxf(s0.z, s0.w));
        #pragma unroll
        for (int off = 32; off; off >>= 1)
            m = fmaxf(m, __shfl_xor(m, off));
        float4 e;
        e.x = __expf(s0.x - m); e.y = __expf(s0.y - m);
        e.z = __expf(s0.z - m); e.w = __expf(s0.w - m);
        *reinterpret_cast<float4*>(&e_lds[w * LK_ + l * 4]) = e;
    }
    __syncthreads();

    // ================= phase 8: masked num/den ==============================
    {
        float num[8] = {0.f, 0.f, 0.f, 0.f, 0.f, 0.f, 0.f, 0.f};
        float den[8] = {0.f, 0.f, 0.f, 0.f, 0.f, 0.f, 0.f, 0.f};
        #pragma unroll
        for (int jq = 0; jq < 4; ++jq) {
            const float4 mv4 = make_float4(mfv[jq*4+0]*vv[jq*4+0], mfv[jq*4+1]*vv[jq*4+1],
                                           mfv[jq*4+2]*vv[jq*4+2], mfv[jq*4+3]*vv[jq*4+3]);
            const float4 mf4 = make_float4(mfv[jq*4+0], mfv[jq*4+1],
                                           mfv[jq*4+2], mfv[jq*4+3]);
            #pragma unroll
            for (int rh = 0; rh < 8; ++rh) {
                float4 ev = *reinterpret_cast<const float4*>(
                    &e_lds[rh * LK_ + kg * 16 + jq * 4]);
                num[rh] = fmaf(ev.x, mv4.x, num[rh]);
                num[rh] = fmaf(ev.y, mv4.y, num[rh]);
                num[rh] = fmaf(ev.z, mv4.z, num[rh]);
                num[rh] = fmaf(ev.w, mv4.w, num[rh]);
                den[rh] = fmaf(ev.x, mf4.x, den[rh]);
                den[rh] = fmaf(ev.y, mf4.y, den[rh]);
                den[rh] = fmaf(ev.z, mf4.z, den[rh]);
                den[rh] = fmaf(ev.w, mf4.w, den[rh]);
            }
        }
        #pragma unroll
        for (int rh = 0; rh < 8; ++rh) {
            nump[(kg * 8 + rh) * 32 + d] = num[rh];
            denp[(kg * 8 + rh) * 32 + d] = den[rh];
        }
    }
    __syncthreads();

    // ================= phase 9: x = num/den =================================
    if (t < 256) {
        const int rh = t >> 5, dd = t & 31;
        float n = 0.f, dn = 0.f;
        #pragma unroll
        for (int k2 = 0; k2 < 16; ++k2) {
            n  += nump[(k2 * 8 + rh) * 32 + dd];
            dn += denp[(k2 * 8 + rh) * 32 + dd];
        }
        x[(rh >> 2) * 128 + (rh & 3) * 32 + dd] = n / dn;
    }
    __syncthreads();

    // ================= phase 10: out projection (Wo from regs) ==============
    {
        const int c0 = slab2 * 32;
        const float4* x40 = reinterpret_cast<const float4*>(x + c0);
        const float4* x41 = reinterpret_cast<const float4*>(x + 128 + c0);
        float acc0o = 0.f, acc1o = 0.f;
        #pragma unroll
        for (int j = 0; j < 8; ++j) {
            float4 xv0 = x40[j];
            float4 xv1 = x41[j];
            const float w0 = wor[j * 4 + 0];
            const float w1 = wor[j * 4 + 1];
            const float w2 = wor[j * 4 + 2];
            const float w3 = wor[j * 4 + 3];
            acc0o = fmaf(xv0.x, w0, acc0o); acc1o = fmaf(xv1.x, w0, acc1o);
            acc0o = fmaf(xv0.y, w1, acc0o); acc1o = fmaf(xv1.y, w1, acc1o);
            acc0o = fmaf(xv0.z, w2, acc0o); acc1o = fmaf(xv1.z, w2, acc1o);
            acc0o = fmaf(xv0.w, w3, acc0o); acc1o = fmaf(xv1.w, w3, acc1o);
        }
        opart[(slab2 * 2 + 0) * 128 + col2] = acc0o;
        opart[(slab2 * 2 + 1) * 128 + col2] = acc1o;
    }
    __syncthreads();

    // ================= phase 11: finalize + store ===========================
    if (t < 256) {
        const int col = t & 127, r = t >> 7;
        float s = bo[col];
        #pragma unroll
        for (int eq = 0; eq < 4; ++eq)
            s += opart[(eq * 2 + r) * 128 + col];
        out[((size_t)(b * LQ_) + q0 + r) * NH_ + col] = s;
    }
}

extern "C" void kernel_launch(void* const* d_in, const int* in_sizes, int n_in,
                              void* d_out, int out_size, void* d_ws, size_t ws_size,
                              hipStream_t stream) {
    const float* query = (const float*)d_in[0];
    const float* key   = (const float*)d_in[1];
    const float* value = (const float*)d_in[2];
    const int*   mask  = (const int*)d_in[3];
    const float* Wq    = (const float*)d_in[4];
    const float* bq    = (const float*)d_in[5];
    const float* Wk    = (const float*)d_in[6];
    // d_in[7] = bk: k-constant in scores -> cancels in softmax -> unused
    const float* Wo    = (const float*)d_in[8];
    const float* bo    = (const float*)d_in[9];
    float* out = (float*)d_out;

    const size_t lds_bytes = 35328 * sizeof(float);   // 138 KB
    static bool attr_set = false;
    if (!attr_set) {
        hipFuncSetAttribute(reinterpret_cast<const void*>(fused_attn_kernel),
                            hipFuncAttributeMaxDynamicSharedMemorySize,
                            (int)lds_bytes);
        attr_set = true;
    }

    fused_attn_kernel<<<B_ * (LQ_ / 2), 512, lds_bytes, stream>>>(
        query, key, value, mask, Wq, bq, Wk, Wo, bo, out);
}